// Round 12
// baseline (200.360 us; speedup 1.0000x reference)
//
#include <hip/hip_runtime.h>
#include <hip/hip_bf16.h>

#define BATCH 8
#define SEQ   2048
#define DIM   512
#define QB    32
#define KB    64
#define NT    512          // 8 waves
#define NKV   (SEQ / KB)   // 32 KV tiles

typedef __attribute__((ext_vector_type(8))) short short8;
typedef __attribute__((ext_vector_type(4))) float f32x4;
typedef __attribute__((ext_vector_type(4))) unsigned short ushort4v;

__device__ __forceinline__ unsigned short f2bf(float f) {
    union { float f; unsigned u; } v; v.f = f;
    return (unsigned short)((v.u + 0x7FFFu + ((v.u >> 16) & 1u)) >> 16);
}

// K-tile row swizzle (validated R4-R11).
__device__ __forceinline__ int swz(int kv) {
    return (8 * (kv & 7)) ^ (16 * ((kv >> 3) & 3)) ^ (64 * ((kv >> 3) & 1));
}

// ---- pre-pass: X fp32 -> Xbf (row-major bf16) + Xt (transposed bf16 [b][d][s])
// (validated R9-R11)
__global__ __launch_bounds__(256)
void prep_kernel(const float* __restrict__ X,
                 unsigned short* __restrict__ Xbf,
                 unsigned short* __restrict__ Xt) {
    __shared__ unsigned short T[64][72];   // [s][d], padded
    const int b  = blockIdx.z;
    const int s0 = blockIdx.x * 64;
    const int d0 = blockIdx.y * 64;
    const int tid = threadIdx.x;
    const float* Xb = X + ((size_t)b * SEQ + s0) * DIM + d0;
    unsigned short* Yb = Xbf + ((size_t)b * SEQ + s0) * DIM + d0;
    #pragma unroll
    for (int r = 0; r < 4; ++r) {
        const int s = (tid >> 4) + r * 16;
        const int d = (tid & 15) * 4;
        float4 v = *(const float4*)(Xb + (size_t)s * DIM + d);
        ushort4v h;
        h[0] = f2bf(v.x); h[1] = f2bf(v.y); h[2] = f2bf(v.z); h[3] = f2bf(v.w);
        *(ushort4v*)(Yb + (size_t)s * DIM + d) = h;
        *(ushort4v*)&T[s][d] = h;
    }
    __syncthreads();
    {
        const int d = tid >> 2;
        const int sc = (tid & 3) * 16;
        unsigned short buf[16];
        #pragma unroll
        for (int j = 0; j < 16; ++j) buf[j] = T[sc + j][d];
        unsigned short* o = Xt + ((size_t)b * DIM + d0 + d) * SEQ + s0 + sc;
        *(short8*)(o)     = *(short8*)&buf[0];
        *(short8*)(o + 8) = *(short8*)&buf[8];
    }
}

// score = X·X^T (no scaling), softmax, out = P·X — flash-style, bf16 MFMA.
// R12 = R7's LDS-saturated skeleton (reg-staged tiles, 4 barriers — best @180us)
//     + R9's transposed-V PV (b128 Vt reads replace the 64x scalar gather).
__global__ __launch_bounds__(NT, 2)
void attn_fwd(const unsigned short* __restrict__ Xbf,
              const unsigned short* __restrict__ Xt,
              float* __restrict__ O) {
    const int b   = blockIdx.x & 7;          // batch -> XCD pinning
    const int qt  = blockIdx.x >> 3;         // 0..63
    const int tid = threadIdx.x;
    const int lane = tid & 63;
    const int w    = tid >> 6;
    const int col  = lane & 15;
    const int kgrp = lane >> 4;

    __shared__ alignas(16) unsigned short Klds[KB * DIM];       // 64 KB, swizzled
    __shared__ alignas(16) unsigned short Vtlds[DIM * KB];      // 64 KB, [d][kv]
    __shared__ alignas(16) float Sbuf[QB][KB + 4];              // 8.7 KB
    __shared__ alignas(16) unsigned short Pfrag[2][2][64][8];   // 4 KB, A-frag layout
    __shared__ float m_s[QB], l_s[QB], fac_s[QB];

    const unsigned short* Xb  = Xbf + (size_t)b * SEQ * DIM;
    const unsigned short* Xtb = Xt  + (size_t)b * DIM * SEQ;

    // ---- Q preload: wave w owns 16 q-rows (strip qs = w>>2), kc strip = w&3
    const int qs = w >> 2;       // 0..1
    const int kc = w & 3;        // 0..3
    short8 qfrag[16];            // 64 VGPR
    {
        const int qrow = qt * QB + qs * 16 + col;
        const unsigned short* qp = Xb + (size_t)qrow * DIM;
        #pragma unroll
        for (int ks = 0; ks < 16; ++ks)
            qfrag[ks] = *(const short8*)(qp + ks * 32 + kgrp * 8);
    }

    if (tid < QB) { m_s[tid] = -INFINITY; l_s[tid] = 0.f; }

    f32x4 oacc[2][4];   // O[32 q][w*64 .. +64 d] : [q2][dt]
    #pragma unroll
    for (int i = 0; i < 2; ++i)
        #pragma unroll
        for (int j = 0; j < 4; ++j)
            oacc[i][j] = (f32x4){0.f, 0.f, 0.f, 0.f};

    for (int t = 0; t < NKV; ++t) {
        __syncthreads();   // (a) prev iter's readers done with Klds/Vtlds
        // ---- stage K tile (bf16 copy, swizzled) — R7's reg-staged pattern;
        // compiler pipelines the 8 loads against the 8 ds_writes.
        {
            const unsigned short* kp = Xb + (size_t)(t * KB) * DIM;
            const int kv = tid >> 3;
            const unsigned short* src = kp + (size_t)kv * DIM + (tid & 7) * 8;
            unsigned short* dst = &Klds[kv * DIM];
            const int sw = swz(kv);
            #pragma unroll
            for (int i = 0; i < 8; ++i) {
                const int d0 = i * 64 + (tid & 7) * 8;
                *(short8*)(dst + (d0 ^ sw)) = *(const short8*)(src + i * 64);
            }
        }
        // ---- stage V^T tile from Xt into Vtlds[d][kv], kv ^= 8*(d&7)
        {
            const unsigned short* vp = Xtb + t * KB;
            #pragma unroll
            for (int k = 0; k < 8; ++k) {
                const int d   = w * 64 + k * 8 + (lane >> 3);
                const int kvc = (lane & 7) * 8;
                short8 v = *(const short8*)(vp + (size_t)d * SEQ + kvc);
                *(short8*)&Vtlds[d * KB + (kvc ^ (8 * (d & 7)))] = v;
            }
        }
        __syncthreads();   // (b) tiles ready

        // ---- QK^T: wave computes S[qs*16 .. +16][kc*16 .. +16]
        {
            const int kvrow = kc * 16 + col;
            const unsigned short* kbase = &Klds[kvrow * DIM];
            const int sw = swz(kvrow);
            f32x4 sacc = (f32x4){0.f,0.f,0.f,0.f};
            #pragma unroll
            for (int ks = 0; ks < 16; ++ks) {
                short8 kfr = *(const short8*)(kbase + ((ks * 32 + kgrp * 8) ^ sw));
                sacc = __builtin_amdgcn_mfma_f32_16x16x32_bf16(qfrag[ks], kfr, sacc, 0, 0, 0);
            }
            #pragma unroll
            for (int r = 0; r < 4; ++r)
                Sbuf[qs * 16 + kgrp * 4 + r][kc * 16 + col] = sacc[r];
        }
        __syncthreads();   // (c) Sbuf ready

        // ---- online softmax: 16 threads/row, 4 scores each
        {
            const int r = tid >> 4;     // 0..31
            const int c = tid & 15;     // 0..15
            float4 sa = *(const float4*)&Sbuf[r][c * 4];
            float mloc = fmaxf(fmaxf(sa.x, sa.y), fmaxf(sa.z, sa.w));
            mloc = fmaxf(mloc, __shfl_xor(mloc, 1));
            mloc = fmaxf(mloc, __shfl_xor(mloc, 2));
            mloc = fmaxf(mloc, __shfl_xor(mloc, 4));
            mloc = fmaxf(mloc, __shfl_xor(mloc, 8));
            const float mold = m_s[r];
            const float mnew = fmaxf(mold, mloc);
            const float fac  = __expf(mold - mnew);   // exp(-inf)=0 on first tile
            float p0 = __expf(sa.x - mnew), p1 = __expf(sa.y - mnew);
            float p2 = __expf(sa.z - mnew), p3 = __expf(sa.w - mnew);
            float lsum = (p0 + p1) + (p2 + p3);
            lsum += __shfl_xor(lsum, 1);
            lsum += __shfl_xor(lsum, 2);
            lsum += __shfl_xor(lsum, 4);
            lsum += __shfl_xor(lsum, 8);
            ushort4v p4;
            p4[0] = f2bf(p0); p4[1] = f2bf(p1); p4[2] = f2bf(p2); p4[3] = f2bf(p3);
            // value (q=r, kv=4c+jj) -> Pfrag[q>>4][kv>>5][(q&15)+16*((kv>>3)&3)][kv&7]
            *(ushort4v*)&Pfrag[r >> 4][c >> 3][(r & 15) + 16 * ((c >> 1) & 3)][(c & 1) * 4] = p4;
            if (c == 0) {
                m_s[r] = mnew;
                fac_s[r] = fac;
                l_s[r] = l_s[r] * fac + lsum;
            }
        }
        __syncthreads();   // (d) Pfrag/fac ready

        // ---- rescale O, then PV: A from Pfrag, B from Vtlds (both b128)
        #pragma unroll
        for (int q2 = 0; q2 < 2; ++q2) {
            #pragma unroll
            for (int r = 0; r < 4; ++r) {
                const float f = fac_s[q2 * 16 + kgrp * 4 + r];
                #pragma unroll
                for (int dt = 0; dt < 4; ++dt) oacc[q2][dt][r] *= f;
            }
        }
        #pragma unroll
        for (int kc2 = 0; kc2 < 2; ++kc2) {
            const int kvb = kc2 * 32 + kgrp * 8;
            short8 afr[2];
            #pragma unroll
            for (int q2 = 0; q2 < 2; ++q2)
                afr[q2] = *(const short8*)&Pfrag[q2][kc2][lane][0];
            #pragma unroll
            for (int dt = 0; dt < 4; ++dt) {
                const int d = w * 64 + dt * 16 + col;
                const short8 bfr = *(const short8*)&Vtlds[d * KB + (kvb ^ (8 * (d & 7)))];
                #pragma unroll
                for (int q2 = 0; q2 < 2; ++q2)
                    oacc[q2][dt] = __builtin_amdgcn_mfma_f32_16x16x32_bf16(afr[q2], bfr, oacc[q2][dt], 0, 0, 0);
            }
        }
    }

    // ---- epilogue: divide by l, store fp32
    #pragma unroll
    for (int q2 = 0; q2 < 2; ++q2) {
        #pragma unroll
        for (int r = 0; r < 4; ++r) {
            const int row = q2 * 16 + kgrp * 4 + r;
            const float inv = 1.f / l_s[row];
            float* op = O + ((size_t)b * SEQ + qt * QB + row) * DIM + w * 64 + col;
            #pragma unroll
            for (int dt = 0; dt < 4; ++dt)
                op[dt * 16] = oacc[q2][dt][r] * inv;
        }
    }
}

extern "C" void kernel_launch(void* const* d_in, const int* in_sizes, int n_in,
                              void* d_out, int out_size, void* d_ws, size_t ws_size,
                              hipStream_t stream) {
    const float* X = (const float*)d_in[0];
    float* Out = (float*)d_out;
    unsigned short* Xbf = (unsigned short*)d_ws;                       // 16.8 MB
    unsigned short* Xt  = Xbf + (size_t)BATCH * SEQ * DIM;             // 16.8 MB

    dim3 pgrid(SEQ / 64, DIM / 64, BATCH);   // 32 x 8 x 8
    hipLaunchKernelGGL(prep_kernel, pgrid, dim3(256), 0, stream, X, Xbf, Xt);

    dim3 grid(BATCH * (SEQ / QB));           // 512 blocks
    dim3 block(NT);
    hipLaunchKernelGGL(attn_fwd, grid, block, 0, stream, Xbf, Xt, Out);
}